// Round 1
// baseline (899.747 us; speedup 1.0000x reference)
//
#include <hip/hip_runtime.h>
#include <hip/hip_bf16.h>

// Problem constants: B=4, M=3, N=2048, DIM=512, H=4, HD=128, SCALE=sqrt(128)
// BM = B*M = 12 ; rows R = BM*N = 24576
// ws layout (bf16): Q [BM][H][N][HD] | K [BM][H][N][HD] | Vt [BM][H][HD][N]

typedef short s16x8 __attribute__((ext_vector_type(8)));
typedef float f32x4 __attribute__((ext_vector_type(4)));

#define MFMA16(a, b, c) __builtin_amdgcn_mfma_f32_16x16x32_bf16((a), (b), (c), 0, 0, 0)

static __device__ __forceinline__ unsigned short f2bf(float f) {
    union { float f; unsigned u; } v; v.f = f;
    unsigned r = v.u + 0x7FFFu + ((v.u >> 16) & 1u);   // RNE
    return (unsigned short)(r >> 16);
}

// ---------------------------------------------------------------------------
// Phase 1: QKV projection. C[r][c] = sum_d X[r][d]*W[c][d] + bias[c]
// 128x128 tile per block, 4 waves in 2x2 of 64x64, BK=64, bf16 MFMA 16x16x32.
// ---------------------------------------------------------------------------
#define PSTR 88   // padded LDS row stride (elements): 176B, 16B-aligned, 2-way bank alias (free)

__global__ __launch_bounds__(256, 2)
void qkv_proj_kernel(const float* __restrict__ Xq, const float* __restrict__ Xk,
                     const float* __restrict__ Xv,
                     const float* __restrict__ Wq, const float* __restrict__ bq,
                     const float* __restrict__ Wk, const float* __restrict__ bk,
                     const float* __restrict__ Wv, const float* __restrict__ bv,
                     unsigned short* __restrict__ ws_q,
                     unsigned short* __restrict__ ws_k,
                     unsigned short* __restrict__ ws_vt)
{
    __shared__ unsigned short As[128 * PSTR];
    __shared__ unsigned short Bs[128 * PSTR];

    const int which = blockIdx.z;
    const float* X    = (which == 0) ? Xq : (which == 1) ? Xk : Xv;
    const float* W    = (which == 0) ? Wq : (which == 1) ? Wk : Wv;
    const float* bias = (which == 0) ? bq : (which == 1) ? bk : bv;

    const int r0 = blockIdx.x * 128;
    const int c0 = blockIdx.y * 128;
    const int tid = threadIdx.x;
    const int lane = tid & 63, wave = tid >> 6;
    const int l15 = lane & 15, quad = lane >> 4;
    const int wr = (wave >> 1) * 64, wc = (wave & 1) * 64;

    f32x4 acc[4][4] = {};

    for (int k0 = 0; k0 < 512; k0 += 64) {
        // stage A (X rows) and B (W rows = output cols): fp32 -> bf16
        for (int i = 0; i < 8; ++i) {
            const int idx = i * 256 + tid;       // 2048 float4s = 128x64 fp32
            const int row = idx >> 4;
            const int col = (idx & 15) * 4;
            float4 fa = *(const float4*)&X[(size_t)(r0 + row) * 512 + k0 + col];
            float4 fb = *(const float4*)&W[(size_t)(c0 + row) * 512 + k0 + col];
            ushort4 sa, sb;
            sa.x = f2bf(fa.x); sa.y = f2bf(fa.y); sa.z = f2bf(fa.z); sa.w = f2bf(fa.w);
            sb.x = f2bf(fb.x); sb.y = f2bf(fb.y); sb.z = f2bf(fb.z); sb.w = f2bf(fb.w);
            *(ushort4*)&As[row * PSTR + col] = sa;
            *(ushort4*)&Bs[row * PSTR + col] = sb;
        }
        __syncthreads();
        for (int kk = 0; kk < 2; ++kk) {
            s16x8 af[4], bf[4];
            for (int mi = 0; mi < 4; ++mi)
                af[mi] = *(const s16x8*)&As[(wr + mi * 16 + l15) * PSTR + kk * 32 + quad * 8];
            for (int ni = 0; ni < 4; ++ni)
                bf[ni] = *(const s16x8*)&Bs[(wc + ni * 16 + l15) * PSTR + kk * 32 + quad * 8];
            for (int mi = 0; mi < 4; ++mi)
                for (int ni = 0; ni < 4; ++ni)
                    acc[mi][ni] = MFMA16(af[mi], bf[ni], acc[mi][ni]);
        }
        __syncthreads();
    }

    // epilogue: +bias, cast bf16, scatter to attention-friendly layouts
    float bvals[4];
    for (int ni = 0; ni < 4; ++ni) bvals[ni] = bias[c0 + wc + ni * 16 + l15];

    for (int mi = 0; mi < 4; ++mi) {
        const int rbase = r0 + wr + mi * 16 + quad * 4;
        for (int ni = 0; ni < 4; ++ni) {
            const int c = c0 + wc + ni * 16 + l15;
            const int h = c >> 7, hd = c & 127;
            for (int r = 0; r < 4; ++r) {
                const int rr = rbase + r;
                const int bm = rr >> 11, n = rr & 2047;
                const unsigned short v = f2bf(acc[mi][ni][r] + bvals[ni]);
                if (which == 0)
                    ws_q[((size_t)(bm * 4 + h) * 2048 + n) * 128 + hd] = v;
                else if (which == 1)
                    ws_k[((size_t)(bm * 4 + h) * 2048 + n) * 128 + hd] = v;
                else
                    ws_vt[(((size_t)(bm * 4 + h)) * 128 + hd) * 2048 + n] = v;
            }
        }
    }
}

// ---------------------------------------------------------------------------
// Phase 2: flash attention per (bm, h, q-tile of 128). 4 waves x 32 rows.
// Bc = 128 keys per iteration, HD = 128. Online softmax in registers.
// Only P goes through LDS (C-layout -> A-layout transform). No __syncthreads.
// ---------------------------------------------------------------------------
#define PPAD 152  // P_lds row stride: 304B, 16B-aligned, 2-way bank alias

__global__ __launch_bounds__(256, 2)
void attn_kernel(const unsigned short* __restrict__ Qw,
                 const unsigned short* __restrict__ Kw,
                 const unsigned short* __restrict__ Vtw,
                 float* __restrict__ out)
{
    __shared__ unsigned short P_lds[128 * PPAD];

    const int q0 = blockIdx.x * 128;
    const int h  = blockIdx.y;
    const int bm = blockIdx.z;
    const int tid = threadIdx.x;
    const int lane = tid & 63, wave = tid >> 6;
    const int l15 = lane & 15, quad = lane >> 4;

    const unsigned short* Qh = Qw  + (size_t)(bm * 4 + h) * 2048 * 128;
    const unsigned short* Kh = Kw  + (size_t)(bm * 4 + h) * 2048 * 128;
    const unsigned short* Vh = Vtw + (size_t)(bm * 4 + h) * 128 * 2048;

    // preload Q fragments (A-operand): rows wave*32 + mi*16 + l15
    s16x8 qf[2][4];
    for (int mi = 0; mi < 2; ++mi)
        for (int kk = 0; kk < 4; ++kk)
            qf[mi][kk] = *(const s16x8*)&Qh[(size_t)(q0 + wave * 32 + mi * 16 + l15) * 128 + kk * 32 + quad * 8];

    f32x4 acc_o[2][8] = {};
    float m_s[2][4], l_s[2][4];
    for (int mi = 0; mi < 2; ++mi)
        for (int r = 0; r < 4; ++r) { m_s[mi][r] = -INFINITY; l_s[mi][r] = 0.f; }

    const float CEXP = 1.4426950408889634f / 11.313708498984761f;  // log2(e)/sqrt(128)

    for (int k0 = 0; k0 < 2048; k0 += 128) {
        // ---- S = Q K^T (raw, unscaled) ----
        f32x4 s[2][8] = {};
        for (int kk = 0; kk < 4; ++kk) {
            s16x8 kf[8];
            for (int ni = 0; ni < 8; ++ni)
                kf[ni] = *(const s16x8*)&Kh[(size_t)(k0 + ni * 16 + l15) * 128 + kk * 32 + quad * 8];
            for (int mi = 0; mi < 2; ++mi)
                for (int ni = 0; ni < 8; ++ni)
                    s[mi][ni] = MFMA16(qf[mi][kk], kf[ni], s[mi][ni]);
        }
        // ---- row max over the 128-key tile ----
        float rmax[2][4];
        for (int mi = 0; mi < 2; ++mi)
            for (int r = 0; r < 4; ++r) {
                float v = s[mi][0][r];
                for (int ni = 1; ni < 8; ++ni) v = fmaxf(v, s[mi][ni][r]);
                rmax[mi][r] = v;
            }
        for (int msk = 1; msk < 16; msk <<= 1)
            for (int mi = 0; mi < 2; ++mi)
                for (int r = 0; r < 4; ++r)
                    rmax[mi][r] = fmaxf(rmax[mi][r], __shfl_xor(rmax[mi][r], msk));

        // ---- online-softmax update ----
        float alpha[2][4], rsum[2][4];
        for (int mi = 0; mi < 2; ++mi)
            for (int r = 0; r < 4; ++r) {
                const float mn = fmaxf(m_s[mi][r], rmax[mi][r]);
                alpha[mi][r] = exp2f((m_s[mi][r] - mn) * CEXP);
                m_s[mi][r] = mn;
                rsum[mi][r] = 0.f;
            }
        // ---- P = exp2((S - m)*CEXP), rowsum, write bf16 P to LDS ----
        for (int mi = 0; mi < 2; ++mi)
            for (int ni = 0; ni < 8; ++ni) {
                const int rowb = wave * 32 + mi * 16 + quad * 4;
                const int col = ni * 16 + l15;
                for (int r = 0; r < 4; ++r) {
                    const float p = exp2f((s[mi][ni][r] - m_s[mi][r]) * CEXP);
                    rsum[mi][r] += p;
                    P_lds[(rowb + r) * PPAD + col] = f2bf(p);
                }
            }
        for (int msk = 1; msk < 16; msk <<= 1)
            for (int mi = 0; mi < 2; ++mi)
                for (int r = 0; r < 4; ++r)
                    rsum[mi][r] += __shfl_xor(rsum[mi][r], msk);
        for (int mi = 0; mi < 2; ++mi)
            for (int r = 0; r < 4; ++r)
                l_s[mi][r] = alpha[mi][r] * l_s[mi][r] + rsum[mi][r];
        for (int mi = 0; mi < 2; ++mi)
            for (int ni = 0; ni < 8; ++ni)
                for (int r = 0; r < 4; ++r)
                    acc_o[mi][ni][r] *= alpha[mi][r];

        // ---- O += P V  (A from P_lds, B from transposed V in global) ----
        for (int kk = 0; kk < 4; ++kk) {
            s16x8 pf[2], vf[8];
            for (int mi = 0; mi < 2; ++mi)
                pf[mi] = *(const s16x8*)&P_lds[(wave * 32 + mi * 16 + l15) * PPAD + kk * 32 + quad * 8];
            for (int ni = 0; ni < 8; ++ni)
                vf[ni] = *(const s16x8*)&Vh[(size_t)(ni * 16 + l15) * 2048 + k0 + kk * 32 + quad * 8];
            for (int mi = 0; mi < 2; ++mi)
                for (int ni = 0; ni < 8; ++ni)
                    acc_o[mi][ni] = MFMA16(pf[mi], vf[ni], acc_o[mi][ni]);
        }
    }

    // ---- epilogue: O / l, fp32 store to (bm, n, h*128+hd) ----
    for (int mi = 0; mi < 2; ++mi)
        for (int r = 0; r < 4; ++r) {
            const float inv = 1.f / l_s[mi][r];
            const int n = q0 + wave * 32 + mi * 16 + quad * 4 + r;
            float* orow = out + ((size_t)bm * 2048 + n) * 512 + h * 128;
            for (int ni = 0; ni < 8; ++ni)
                orow[ni * 16 + l15] = acc_o[mi][ni][r] * inv;
        }
}

extern "C" void kernel_launch(void* const* d_in, const int* in_sizes, int n_in,
                              void* d_out, int out_size, void* d_ws, size_t ws_size,
                              hipStream_t stream) {
    const float* Xq = (const float*)d_in[0];
    const float* Xk = (const float*)d_in[1];
    const float* Xv = (const float*)d_in[2];
    const float* Wq = (const float*)d_in[3];
    const float* bq = (const float*)d_in[4];
    const float* Wk = (const float*)d_in[5];
    const float* bk = (const float*)d_in[6];
    const float* Wv = (const float*)d_in[7];
    const float* bv = (const float*)d_in[8];
    float* out = (float*)d_out;

    unsigned short* ws = (unsigned short*)d_ws;
    const size_t per_tensor = (size_t)12 * 4 * 2048 * 128;  // 12.58M bf16 each
    unsigned short* ws_q  = ws;
    unsigned short* ws_k  = ws + per_tensor;
    unsigned short* ws_vt = ws + 2 * per_tensor;

    // Phase 1: 192 row-tiles x 4 col-tiles x {Q,K,V}
    qkv_proj_kernel<<<dim3(192, 4, 3), 256, 0, stream>>>(
        Xq, Xk, Xv, Wq, bq, Wk, bk, Wv, bv, ws_q, ws_k, ws_vt);

    // Phase 2: 16 q-tiles x 4 heads x 12 (b,m)
    attn_kernel<<<dim3(16, 4, 12), 256, 0, stream>>>(ws_q, ws_k, ws_vt, out);
}